// Round 1
// 306.892 us; speedup vs baseline: 1.0649x; 1.0649x over previous
//
#include <hip/hip_runtime.h>

// Problem constants (B=4, L=4096, E=512, H=16, D=32)
#define EMBED  512
#define NHEAD  16
#define HDIM   32
#define NBATCH 4
#define SEQ    4096
#define NROWS  (NBATCH * SEQ)   // 16384
#define NE     (NROWS * EMBED)  // 8388608 elements per activation tensor
#define WN     (EMBED * EMBED)  // 262144 elements per weight
#define FEPS   1e-6f

typedef __attribute__((ext_vector_type(8))) short short8;
typedef __attribute__((ext_vector_type(4))) float f32x4;

// ---- bf16 split helpers (RNE) ----
__device__ __forceinline__ short f2bf(float x) {
    unsigned u = __float_as_uint(x);
    u += 0x7FFFu + ((u >> 16) & 1u);
    return (short)(u >> 16);
}
__device__ __forceinline__ float bf2f(short h) {
    return __uint_as_float(((unsigned)(unsigned short)h) << 16);
}

// async global->LDS, 16B per lane, wave-uniform LDS base + lane*16
#define GLDS16(gp, lp)                                                   \
    __builtin_amdgcn_global_load_lds(                                    \
        (__attribute__((address_space(1))) void*)(void*)(gp),            \
        (__attribute__((address_space(3))) void*)(void*)(lp), 16, 0, 0)

// ---- convert everything fp32 -> split bf16 (hi/lo planes), one pass ------
// segs: 3 inputs (4096 blocks each), 4 weights (128 blocks each). 8 floats/thr.
__global__ __launch_bounds__(256)
void convert_all(const float* __restrict__ q, const float* __restrict__ k,
                 const float* __restrict__ v,
                 const float* __restrict__ wq, const float* __restrict__ wk,
                 const float* __restrict__ wv, const float* __restrict__ wm,
                 short* __restrict__ qh, short* __restrict__ ql,
                 short* __restrict__ kh, short* __restrict__ kl,
                 short* __restrict__ vh, short* __restrict__ vl,
                 short* __restrict__ wqh, short* __restrict__ wql,
                 short* __restrict__ wkh, short* __restrict__ wkl,
                 short* __restrict__ wvh, short* __restrict__ wvl,
                 short* __restrict__ wmh, short* __restrict__ wml) {
    const int b = blockIdx.x;
    const float* src; short* dh; short* dl; int boff;
    if (b < 12288) {
        const int s = b >> 12;
        src = (s == 0) ? q  : (s == 1) ? k  : v;
        dh  = (s == 0) ? qh : (s == 1) ? kh : vh;
        dl  = (s == 0) ? ql : (s == 1) ? kl : vl;
        boff = b & 4095;
    } else {
        const int s = (b - 12288) >> 7;
        src = (s == 0) ? wq  : (s == 1) ? wk  : (s == 2) ? wv  : wm;
        dh  = (s == 0) ? wqh : (s == 1) ? wkh : (s == 2) ? wvh : wmh;
        dl  = (s == 0) ? wql : (s == 1) ? wkl : (s == 2) ? wvl : wml;
        boff = (b - 12288) & 127;
    }
    const size_t i = ((size_t)boff * 256 + threadIdx.x) * 8;
    float4 x0 = *(const float4*)(src + i);
    float4 x1 = *(const float4*)(src + i + 4);
    float vv[8] = {x0.x, x0.y, x0.z, x0.w, x1.x, x1.y, x1.z, x1.w};
    short8 h, l;
#pragma unroll
    for (int t = 0; t < 8; ++t) {
        short hb = f2bf(vv[t]);
        h[t] = hb;
        l[t] = f2bf(vv[t] - bf2f(hb));
    }
    *(short8*)(dh + i) = h;
    *(short8*)(dl + i) = l;
}

// ---- fused QKV projection GEMM, m97 structure ----------------------------
// 128x128 tile, 4 waves 2x2, A AND B staged via global_load_lds from
// pre-split bf16 planes. Linear LDS [4][128][32] + XOR chunk swizzle
// (chunk ^= (row>>1)&3) applied on BOTH the global source address and the
// fragment read -> 2-way banked ds_read_b128 (free). Single buffer,
// 2 barriers/K-step; (256,3) => 3 blocks/CU hides the vmcnt drain.
__global__ __launch_bounds__(256, 3)
void qkv_gemm(const short* __restrict__ Aqh, const short* __restrict__ Aql,
              const short* __restrict__ Akh, const short* __restrict__ Akl,
              const short* __restrict__ Avh, const short* __restrict__ Avl,
              const short* __restrict__ WqH, const short* __restrict__ WqL,
              const short* __restrict__ WkH, const short* __restrict__ WkL,
              const short* __restrict__ WvH, const short* __restrict__ WvL,
              float* __restrict__ Qb, float* __restrict__ Kb,
              float* __restrict__ Vb) {
    __shared__ short lds[4][128][32];   // [Ah,Al,Bh,Bl][row][k] = 32 KiB

    const int tid  = threadIdx.x;
    const int lane = tid & 63;
    const int wave = tid >> 6;
    const int wm   = (wave >> 1) * 64;
    const int wn   = (wave & 1) * 64;
    const int l15  = lane & 15;
    const int kg   = lane >> 4;

    const int lin = blockIdx.x;
    const int op  = lin >> 9;                    // 0=q,1=k,2=v
    const int r_  = lin & 511;
    const int bn  = (r_ >> 7) * 128;             // y-major swizzle (L2/XCD)
    const int bm  = (r_ & 127) * 128;

    const short* Ah = (op == 0) ? Aqh : (op == 1) ? Akh : Avh;
    const short* Al = (op == 0) ? Aql : (op == 1) ? Akl : Avl;
    const short* Bh = (op == 0) ? WqH : (op == 1) ? WkH : WvH;
    const short* Bl = (op == 0) ? WqL : (op == 1) ? WkL : WvL;
    float* C = (op == 0) ? Qb : (op == 1) ? Kb : Vb;

    // staging: lane covers (row = wave*32 + q*16 + (lane>>2), chunk = lane&3)
    // source chunk is XOR-swizzled so the fragment read can de-swizzle.
    const int sr = lane >> 2;
    const int sc = (((lane & 3) ^ ((lane >> 3) & 3)) << 3);
    const int rt = wave * 32 + sr;
    const short* gAh = Ah + (size_t)(bm + rt) * EMBED + sc;
    const short* gAl = Al + (size_t)(bm + rt) * EMBED + sc;
    const short* gBh = Bh + (size_t)(bn + rt) * EMBED + sc;
    const short* gBl = Bl + (size_t)(bn + rt) * EMBED + sc;

    short* dAh = &lds[0][wave * 32][0];
    short* dAl = &lds[1][wave * 32][0];
    short* dBh = &lds[2][wave * 32][0];
    short* dBl = &lds[3][wave * 32][0];

    // fragment read chunk (de-swizzle): kg ^ ((row&15)>>1)&3
    const int rk = ((kg ^ ((l15 >> 1) & 3)) << 3);

    f32x4 acc[4][4];
#pragma unroll
    for (int i = 0; i < 4; ++i)
#pragma unroll
        for (int j = 0; j < 4; ++j) acc[i][j] = (f32x4)0.0f;

#pragma unroll 1
    for (int k0 = 0; k0 < EMBED; k0 += 32) {
        GLDS16(gAh + k0,              dAh);
        GLDS16(gAh + 16 * EMBED + k0, dAh + 512);
        GLDS16(gAl + k0,              dAl);
        GLDS16(gAl + 16 * EMBED + k0, dAl + 512);
        GLDS16(gBh + k0,              dBh);
        GLDS16(gBh + 16 * EMBED + k0, dBh + 512);
        GLDS16(gBl + k0,              dBl);
        GLDS16(gBl + 16 * EMBED + k0, dBl + 512);
        __syncthreads();                         // vmcnt(0) drain -> tile ready

        short8 ahv[4], alv[4], bhv[4], blv[4];
#pragma unroll
        for (int i = 0; i < 4; ++i) {
            ahv[i] = *(const short8*)&lds[0][wm + i * 16 + l15][rk];
            alv[i] = *(const short8*)&lds[1][wm + i * 16 + l15][rk];
            bhv[i] = *(const short8*)&lds[2][wn + i * 16 + l15][rk];
            blv[i] = *(const short8*)&lds[3][wn + i * 16 + l15][rk];
        }
#pragma unroll
        for (int i = 0; i < 4; ++i)
#pragma unroll
            for (int j = 0; j < 4; ++j) {
                acc[i][j] = __builtin_amdgcn_mfma_f32_16x16x32_bf16(ahv[i], bhv[j], acc[i][j], 0, 0, 0);
                acc[i][j] = __builtin_amdgcn_mfma_f32_16x16x32_bf16(ahv[i], blv[j], acc[i][j], 0, 0, 0);
                acc[i][j] = __builtin_amdgcn_mfma_f32_16x16x32_bf16(alv[i], bhv[j], acc[i][j], 0, 0, 0);
            }
        __syncthreads();                         // readers done before next stage
    }

    // epilogue: proven direct scalar stores (C/D: col=lane&15, row=(lane>>4)*4+r)
#pragma unroll
    for (int i = 0; i < 4; ++i)
#pragma unroll
        for (int j = 0; j < 4; ++j) {
            const int col = bn + wn + j * 16 + l15;
#pragma unroll
            for (int r = 0; r < 4; ++r) {
                const int row = bm + wm + i * 16 + kg * 4 + r;
                float vv = acc[i][j][r];
                if (op < 2) vv = (vv > 0.f) ? (vv + 1.f) : __expf(vv);
                else        vv = vv * (1.0f / (float)SEQ);
                C[(size_t)row * EMBED + col] = vv;
            }
        }
}

// ---- merge GEMM: same m97 structure, A = message planes ------------------
__global__ __launch_bounds__(256, 3)
void merge_gemm(const short* __restrict__ Mh, const short* __restrict__ Ml,
                const short* __restrict__ WhP, const short* __restrict__ WlP,
                float* __restrict__ C) {
    __shared__ short lds[4][128][32];

    const int tid  = threadIdx.x;
    const int lane = tid & 63;
    const int wave = tid >> 6;
    const int wm   = (wave >> 1) * 64;
    const int wn   = (wave & 1) * 64;
    const int l15  = lane & 15;
    const int kg   = lane >> 4;

    const int lin = blockIdx.x;
    const int bn  = (lin >> 7) * 128;
    const int bm  = (lin & 127) * 128;

    const int sr = lane >> 2;
    const int sc = (((lane & 3) ^ ((lane >> 3) & 3)) << 3);
    const int rt = wave * 32 + sr;
    const short* gAh = Mh  + (size_t)(bm + rt) * EMBED + sc;
    const short* gAl = Ml  + (size_t)(bm + rt) * EMBED + sc;
    const short* gBh = WhP + (size_t)(bn + rt) * EMBED + sc;
    const short* gBl = WlP + (size_t)(bn + rt) * EMBED + sc;

    short* dAh = &lds[0][wave * 32][0];
    short* dAl = &lds[1][wave * 32][0];
    short* dBh = &lds[2][wave * 32][0];
    short* dBl = &lds[3][wave * 32][0];

    const int rk = ((kg ^ ((l15 >> 1) & 3)) << 3);

    f32x4 acc[4][4];
#pragma unroll
    for (int i = 0; i < 4; ++i)
#pragma unroll
        for (int j = 0; j < 4; ++j) acc[i][j] = (f32x4)0.0f;

#pragma unroll 1
    for (int k0 = 0; k0 < EMBED; k0 += 32) {
        GLDS16(gAh + k0,              dAh);
        GLDS16(gAh + 16 * EMBED + k0, dAh + 512);
        GLDS16(gAl + k0,              dAl);
        GLDS16(gAl + 16 * EMBED + k0, dAl + 512);
        GLDS16(gBh + k0,              dBh);
        GLDS16(gBh + 16 * EMBED + k0, dBh + 512);
        GLDS16(gBl + k0,              dBl);
        GLDS16(gBl + 16 * EMBED + k0, dBl + 512);
        __syncthreads();

        short8 ahv[4], alv[4], bhv[4], blv[4];
#pragma unroll
        for (int i = 0; i < 4; ++i) {
            ahv[i] = *(const short8*)&lds[0][wm + i * 16 + l15][rk];
            alv[i] = *(const short8*)&lds[1][wm + i * 16 + l15][rk];
            bhv[i] = *(const short8*)&lds[2][wn + i * 16 + l15][rk];
            blv[i] = *(const short8*)&lds[3][wn + i * 16 + l15][rk];
        }
#pragma unroll
        for (int i = 0; i < 4; ++i)
#pragma unroll
            for (int j = 0; j < 4; ++j) {
                acc[i][j] = __builtin_amdgcn_mfma_f32_16x16x32_bf16(ahv[i], bhv[j], acc[i][j], 0, 0, 0);
                acc[i][j] = __builtin_amdgcn_mfma_f32_16x16x32_bf16(ahv[i], blv[j], acc[i][j], 0, 0, 0);
                acc[i][j] = __builtin_amdgcn_mfma_f32_16x16x32_bf16(alv[i], bhv[j], acc[i][j], 0, 0, 0);
            }
        __syncthreads();
    }

#pragma unroll
    for (int i = 0; i < 4; ++i)
#pragma unroll
        for (int j = 0; j < 4; ++j) {
            const int col = bn + wn + j * 16 + l15;
#pragma unroll
            for (int r = 0; r < 4; ++r) {
                const int row = bm + wm + i * 16 + kg * 4 + r;
                C[(size_t)row * EMBED + col] = acc[i][j][r];
            }
        }
}

// ---- KV + Ksum via split-bf16 MFMA (unchanged, fp32 inputs) --------------
__global__ __launch_bounds__(256)
void kv_ksum_mfma(const float* __restrict__ Kf, const float* __restrict__ Vf,
                  float* __restrict__ KV, float* __restrict__ Ksum) {
    __shared__ char smem[34816];
    short (*Kh)[34] = (short (*)[34])smem;
    short (*Kl)[34] = (short (*)[34])(smem + 8704);
    short (*Vh)[34] = (short (*)[34])(smem + 17408);
    short (*Vl)[34] = (short (*)[34])(smem + 26112);

    const int bh_ = blockIdx.y;
    const int b = bh_ >> 4, h = bh_ & 15;
    const int s0 = blockIdx.x * 256;
    const int t = threadIdx.x;
    const int lane = t & 63, wave = t >> 6;
    const int l15 = lane & 15, kg = lane >> 4;
    const int ws = wave * 32;

    const int sl = t >> 1;
    const int dsel = (t & 1) * 16;
    const float* Kbase = Kf + (size_t)b * SEQ * EMBED + h * HDIM;
    const float* Vbase = Vf + (size_t)b * SEQ * EMBED + h * HDIM;

    f32x4 kvacc[2][2], ksacc[2];
#pragma unroll
    for (int i = 0; i < 2; ++i) {
        ksacc[i] = (f32x4)0.0f;
#pragma unroll
        for (int j = 0; j < 2; ++j) kvacc[i][j] = (f32x4)0.0f;
    }
    short8 ones;
#pragma unroll
    for (int q = 0; q < 8; ++q) ones[q] = (short)0x3F80;   // bf16 1.0

    float4 kx[4], vx[4];
#pragma unroll
    for (int p = 0; p < 4; ++p) {
        kx[p] = *(const float4*)(Kbase + (size_t)(s0 + sl) * EMBED + dsel + 4 * p);
        vx[p] = *(const float4*)(Vbase + (size_t)(s0 + sl) * EMBED + dsel + 4 * p);
    }

#pragma unroll 1
    for (int it = 0; it < 2; ++it) {
        __syncthreads();
        {
            float kv_[8] = {kx[0].x, kx[0].y, kx[0].z, kx[0].w, kx[1].x, kx[1].y, kx[1].z, kx[1].w};
            float kv2[8] = {kx[2].x, kx[2].y, kx[2].z, kx[2].w, kx[3].x, kx[3].y, kx[3].z, kx[3].w};
            float vv_[8] = {vx[0].x, vx[0].y, vx[0].z, vx[0].w, vx[1].x, vx[1].y, vx[1].z, vx[1].w};
            float vv2[8] = {vx[2].x, vx[2].y, vx[2].z, vx[2].w, vx[3].x, vx[3].y, vx[3].z, vx[3].w};
            short8 h0, l0, h1, l1;
#pragma unroll
            for (int q = 0; q < 8; ++q) { short hb = f2bf(kv_[q]); h0[q] = hb; l0[q] = f2bf(kv_[q] - bf2f(hb)); }
#pragma unroll
            for (int q = 0; q < 8; ++q) { short hb = f2bf(kv2[q]); h1[q] = hb; l1[q] = f2bf(kv2[q] - bf2f(hb)); }
            *(short8*)&Kh[sl][dsel] = h0; *(short8*)&Kh[sl][dsel + 8] = h1;
            *(short8*)&Kl[sl][dsel] = l0; *(short8*)&Kl[sl][dsel + 8] = l1;
#pragma unroll
            for (int q = 0; q < 8; ++q) { short hb = f2bf(vv_[q]); h0[q] = hb; l0[q] = f2bf(vv_[q] - bf2f(hb)); }
#pragma unroll
            for (int q = 0; q < 8; ++q) { short hb = f2bf(vv2[q]); h1[q] = hb; l1[q] = f2bf(vv2[q] - bf2f(hb)); }
            *(short8*)&Vh[sl][dsel] = h0; *(short8*)&Vh[sl][dsel + 8] = h1;
            *(short8*)&Vl[sl][dsel] = l0; *(short8*)&Vl[sl][dsel + 8] = l1;
        }
        __syncthreads();
        if (it == 0) {
#pragma unroll
            for (int p = 0; p < 4; ++p) {
                kx[p] = *(const float4*)(Kbase + (size_t)(s0 + 128 + sl) * EMBED + dsel + 4 * p);
                vx[p] = *(const float4*)(Vbase + (size_t)(s0 + 128 + sl) * EMBED + dsel + 4 * p);
            }
        }
        short8 kah[2], kal[2], vbh[2], vbl[2];
#pragma unroll
        for (int i = 0; i < 2; ++i) {
#pragma unroll
            for (int q = 0; q < 8; ++q) {
                const int srow = ws + kg * 8 + q;
                const int col  = i * 16 + l15;
                kah[i][q] = Kh[srow][col];
                kal[i][q] = Kl[srow][col];
                vbh[i][q] = Vh[srow][col];
                vbl[i][q] = Vl[srow][col];
            }
        }
#pragma unroll
        for (int i = 0; i < 2; ++i) {
#pragma unroll
            for (int j = 0; j < 2; ++j) {
                kvacc[i][j] = __builtin_amdgcn_mfma_f32_16x16x32_bf16(kah[i], vbh[j], kvacc[i][j], 0, 0, 0);
                kvacc[i][j] = __builtin_amdgcn_mfma_f32_16x16x32_bf16(kah[i], vbl[j], kvacc[i][j], 0, 0, 0);
                kvacc[i][j] = __builtin_amdgcn_mfma_f32_16x16x32_bf16(kal[i], vbh[j], kvacc[i][j], 0, 0, 0);
            }
            ksacc[i] = __builtin_amdgcn_mfma_f32_16x16x32_bf16(kah[i], ones, ksacc[i], 0, 0, 0);
            ksacc[i] = __builtin_amdgcn_mfma_f32_16x16x32_bf16(kal[i], ones, ksacc[i], 0, 0, 0);
        }
    }

    __syncthreads();
    float* red = (float*)smem;
    float* myred = red + wave * 1056;
#pragma unroll
    for (int i = 0; i < 2; ++i)
#pragma unroll
        for (int j = 0; j < 2; ++j)
#pragma unroll
            for (int r = 0; r < 4; ++r)
                myred[(i * 16 + kg * 4 + r) * 32 + j * 16 + l15] = kvacc[i][j][r];
    if (l15 == 0) {
#pragma unroll
        for (int i = 0; i < 2; ++i)
#pragma unroll
            for (int r = 0; r < 4; ++r)
                myred[1024 + i * 16 + kg * 4 + r] = ksacc[i][r];
    }
    __syncthreads();
    float* kvout = KV + (size_t)bh_ * 1024;
    for (int idx = t; idx < 1024; idx += 256) {
        float s4 = red[idx] + red[1056 + idx] + red[2112 + idx] + red[3168 + idx];
        atomicAdd(&kvout[idx], s4);
    }
    if (t < 32) {
        float s4 = red[1024 + t] + red[1056 + 1024 + t] + red[2112 + 1024 + t] + red[3168 + 1024 + t];
        atomicAdd(&Ksum[bh_ * 32 + t], s4);
    }
}

// ---- message: M[l,h,:] = (SEQ/(Q.Ksum+eps)) * Q @ KV[b,h], emit split bf16
__global__ __launch_bounds__(512)
void message_kernel(const float* __restrict__ Q, const float* __restrict__ KV,
                    const float* __restrict__ Ksum,
                    short* __restrict__ Mh, short* __restrict__ Ml) {
    const int blk  = blockIdx.x;
    const int row0 = blk * 4;
    const int b    = row0 >> 12;
    const int t    = threadIdx.x;
    const int h    = t >> 5, e = t & 31;

    __shared__ float q[4][EMBED];
    __shared__ float ks[EMBED];
    ks[t] = Ksum[b * EMBED + t];
#pragma unroll
    for (int r = 0; r < 4; ++r) q[r][t] = Q[(size_t)(row0 + r) * EMBED + t];

    const float* kvh = KV + (size_t)(b * NHEAD + h) * HDIM * HDIM + e;
    float kc[HDIM];
#pragma unroll
    for (int d = 0; d < HDIM; ++d) kc[d] = kvh[d * HDIM];
    __syncthreads();

#pragma unroll
    for (int r = 0; r < 4; ++r) {
        float zden = FEPS, m = 0.f;
#pragma unroll
        for (int d = 0; d < HDIM; ++d) {
            float qd = q[r][h * HDIM + d];
            zden = fmaf(qd, ks[h * HDIM + d], zden);
            m    = fmaf(qd, kc[d], m);
        }
        float vv = m * ((float)SEQ / zden);
        short hb = f2bf(vv);
        Mh[(size_t)(row0 + r) * EMBED + t] = hb;
        Ml[(size_t)(row0 + r) * EMBED + t] = f2bf(vv - bf2f(hb));
    }
}

// ---- launch ----
extern "C" void kernel_launch(void* const* d_in, const int* in_sizes, int n_in,
                              void* d_out, int out_size, void* d_ws, size_t ws_size,
                              hipStream_t stream) {
    const float* query = (const float*)d_in[0];
    const float* key   = (const float*)d_in[1];
    const float* value = (const float*)d_in[2];
    const float* Wq    = (const float*)d_in[3];
    const float* Wk    = (const float*)d_in[4];
    const float* Wv    = (const float*)d_in[5];
    const float* Wm    = (const float*)d_in[6];
    float* out = (float*)d_out;

    float* ws  = (float*)d_ws;
    float* Qb  = ws;                              // NE fp32
    float* Kb  = Qb + (size_t)NE;                 // NE fp32 (reused as M planes)
    float* Vb  = Kb + (size_t)NE;                 // NE fp32
    float* KVb = Vb + (size_t)NE;                 // 64*1024
    float* KSb = KVb + 64 * 1024;                 // 64*32
    short* wsp = (short*)(KSb + 64 * HDIM);
    short* WqH = wsp;            short* WqL = wsp + WN;
    short* WkH = wsp + 2 * WN;   short* WkL = wsp + 3 * WN;
    short* WvH = wsp + 4 * WN;   short* WvL = wsp + 5 * WN;
    short* WmH = wsp + 6 * WN;   short* WmL = wsp + 7 * WN;
    short* Xp  = wsp + 8 * WN;                    // 6 input planes, NE shorts each
    short* Qih = Xp;             short* Qil = Xp + (size_t)NE;
    short* Kih = Xp + 2 * (size_t)NE;  short* Kil = Xp + 3 * (size_t)NE;
    short* Vih = Xp + 4 * (size_t)NE;  short* Vil = Xp + 5 * (size_t)NE;
    // message planes alias Kb (dead after kv_ksum): 2*NE shorts == NE floats
    short* Mh = (short*)Kb;
    short* Ml = Mh + (size_t)NE;

    hipMemsetAsync(KVb, 0, (64 * 1024 + 64 * HDIM) * sizeof(float), stream);

    convert_all<<<12800, 256, 0, stream>>>(query, key, value, Wq, Wk, Wv, Wm,
                                           Qih, Qil, Kih, Kil, Vih, Vil,
                                           WqH, WqL, WkH, WkL,
                                           WvH, WvL, WmH, WmL);

    qkv_gemm<<<1536, 256, 0, stream>>>(Qih, Qil, Kih, Kil, Vih, Vil,
                                       WqH, WqL, WkH, WkL, WvH, WvL,
                                       Qb, Kb, Vb);

    kv_ksum_mfma<<<dim3(16, 64), 256, 0, stream>>>(Kb, Vb, KVb, KSb);
    message_kernel<<<NROWS / 4, 512, 0, stream>>>(Qb, KVb, KSb, Mh, Ml);

    merge_gemm<<<512, 256, 0, stream>>>(Mh, Ml, WmH, WmL, out);
}

// Round 2
// 303.076 us; speedup vs baseline: 1.0783x; 1.0126x over previous
//
#include <hip/hip_runtime.h>

// Problem constants (B=4, L=4096, E=512, H=16, D=32)
#define EMBED  512
#define NHEAD  16
#define HDIM   32
#define NBATCH 4
#define SEQ    4096
#define NROWS  (NBATCH * SEQ)   // 16384
#define NE     (NROWS * EMBED)  // 8388608 elements per activation tensor
#define WN     (EMBED * EMBED)  // 262144 elements per weight
#define FEPS   1e-6f

typedef __attribute__((ext_vector_type(8))) short short8;
typedef __attribute__((ext_vector_type(4))) float f32x4;

// ---- bf16 split helpers (RNE) ----
__device__ __forceinline__ short f2bf(float x) {
    unsigned u = __float_as_uint(x);
    u += 0x7FFFu + ((u >> 16) & 1u);
    return (short)(u >> 16);
}
__device__ __forceinline__ float bf2f(short h) {
    return __uint_as_float(((unsigned)(unsigned short)h) << 16);
}

// async global->LDS, 16B per lane, wave-uniform LDS base + lane*16
#define GLDS16(gp, lp)                                                   \
    __builtin_amdgcn_global_load_lds(                                    \
        (__attribute__((address_space(1))) void*)(void*)(gp),            \
        (__attribute__((address_space(3))) void*)(void*)(lp), 16, 0, 0)

// ---- convert everything fp32 -> split bf16 (hi/lo planes), one pass ------
__global__ __launch_bounds__(256)
void convert_all(const float* __restrict__ q, const float* __restrict__ k,
                 const float* __restrict__ v,
                 const float* __restrict__ wq, const float* __restrict__ wk,
                 const float* __restrict__ wv, const float* __restrict__ wm,
                 short* __restrict__ qh, short* __restrict__ ql,
                 short* __restrict__ kh, short* __restrict__ kl,
                 short* __restrict__ vh, short* __restrict__ vl,
                 short* __restrict__ wqh, short* __restrict__ wql,
                 short* __restrict__ wkh, short* __restrict__ wkl,
                 short* __restrict__ wvh, short* __restrict__ wvl,
                 short* __restrict__ wmh, short* __restrict__ wml) {
    const int b = blockIdx.x;
    const float* src; short* dh; short* dl; int boff;
    if (b < 12288) {
        const int s = b >> 12;
        src = (s == 0) ? q  : (s == 1) ? k  : v;
        dh  = (s == 0) ? qh : (s == 1) ? kh : vh;
        dl  = (s == 0) ? ql : (s == 1) ? kl : vl;
        boff = b & 4095;
    } else {
        const int s = (b - 12288) >> 7;
        src = (s == 0) ? wq  : (s == 1) ? wk  : (s == 2) ? wv  : wm;
        dh  = (s == 0) ? wqh : (s == 1) ? wkh : (s == 2) ? wvh : wmh;
        dl  = (s == 0) ? wql : (s == 1) ? wkl : (s == 2) ? wvl : wml;
        boff = (b - 12288) & 127;
    }
    const size_t i = ((size_t)boff * 256 + threadIdx.x) * 8;
    float4 x0 = *(const float4*)(src + i);
    float4 x1 = *(const float4*)(src + i + 4);
    float vv[8] = {x0.x, x0.y, x0.z, x0.w, x1.x, x1.y, x1.z, x1.w};
    short8 h, l;
#pragma unroll
    for (int t = 0; t < 8; ++t) {
        short hb = f2bf(vv[t]);
        h[t] = hb;
        l[t] = f2bf(vv[t] - bf2f(hb));
    }
    *(short8*)(dh + i) = h;
    *(short8*)(dl + i) = l;
}

// ---- K-sliced ring-3 counted-vmcnt GEMM core (T3+T4+T5) ------------------
// BM=256 x BN=128 per block, 8 waves (4M x 2N), per-wave 64x64 (4x4 frags).
// K = 512 = 16 slices of 32. LDS ring: 3 slots x {Ah[256][32] Al[256][32]
// Bh[128][32] Bl[128][32]} = 3 x 48KB = 144KB. Phase s: vmcnt(6) [waits only
// slice s; slice s+1 stays in flight], s_barrier, ds_read 16xb128 frags,
// glds-stage slice s+2 into slot (s-1)%3 (readers passed this barrier),
// setprio(1), 48 MFMA, setprio(0). Never drains vmcnt to 0 until last slice.
// Swizzle pair (source chunk ^ (lane>>3)&3 / read chunk kg ^ (l15>>1)&3) is
// byte-identical to the round-1-proven 0-conflict mapping.
__device__ __forceinline__ void gemm_core(
    const short* __restrict__ Ahp, const short* __restrict__ Alp,
    const short* __restrict__ Bhp, const short* __restrict__ Blp,
    int bmG, int bnG, short (*lds)[24576], f32x4 acc[4][4])
{
    const int tid  = threadIdx.x;
    const int lane = tid & 63;
    const int wave = tid >> 6;          // 0..7
    const int l15  = lane & 15;
    const int kg   = lane >> 4;

    // staging source bases (shorts), pre-swizzled chunk
    const int sc8 = (((lane & 3) ^ ((lane >> 3) & 3)) << 3);
    const size_t aR0 = (size_t)(bmG + wave * 32 + (lane >> 2)) * EMBED + sc8;
    const size_t bR0 = (size_t)(bnG + wave * 16 + (lane >> 2)) * EMBED + sc8;

    // LDS staging dest offsets within a slot (shorts)
    const int dA = wave * 1024;         // rows w*32.. ; second issue +512
    const int dB = wave * 512;          // rows w*16..

    // fragment read offsets (de-swizzle)
    const int rk8   = ((kg ^ ((l15 >> 1) & 3)) << 3);
    const int aBase = ((wave >> 1) * 64 + l15) * 32 + rk8;          // Ah; Al = +8192
    const int bBase = 16384 + ((wave & 1) * 64 + l15) * 32 + rk8;   // Bh; Bl = +4096

    // prologue: stage slices 0,1 into slots 0,1 (6 glds each per wave)
#pragma unroll
    for (int v = 0; v < 2; ++v) {
        short* T = lds[v];
        const int kp = v * 32;
        GLDS16(Ahp + aR0 + kp,              T + dA);
        GLDS16(Ahp + aR0 + 16 * EMBED + kp, T + dA + 512);
        GLDS16(Alp + aR0 + kp,              T + 8192 + dA);
        GLDS16(Alp + aR0 + 16 * EMBED + kp, T + 8192 + dA + 512);
        GLDS16(Bhp + bR0 + kp,              T + 16384 + dB);
        GLDS16(Blp + bR0 + kp,              T + 20480 + dB);
    }

    int rs = 0;                          // read slot = s % 3
#pragma unroll 1
    for (int s = 0; s < 16; ++s) {
        if (s < 15) asm volatile("s_waitcnt vmcnt(6)" ::: "memory");
        else        asm volatile("s_waitcnt vmcnt(0)" ::: "memory");
        __builtin_amdgcn_s_barrier();
        __builtin_amdgcn_sched_barrier(0);   // no load may hoist above barrier

        short* S = lds[rs];
        short8 fah[4], fal[4], fbh[4], fbl[4];
#pragma unroll
        for (int f = 0; f < 4; ++f) {
            fah[f] = *(const short8*)(S + aBase + f * 512);
            fal[f] = *(const short8*)(S + 8192 + aBase + f * 512);
            fbh[f] = *(const short8*)(S + bBase + f * 512);
            fbl[f] = *(const short8*)(S + 4096 + bBase + f * 512);
        }
        if (s < 14) {                    // stage slice s+2 -> slot (rs+2)%3
            const int ws2 = (rs + 2 >= 3) ? (rs - 1) : (rs + 2);
            short* T = lds[ws2];
            const int kp = (s + 2) * 32;
            GLDS16(Ahp + aR0 + kp,              T + dA);
            GLDS16(Ahp + aR0 + 16 * EMBED + kp, T + dA + 512);
            GLDS16(Alp + aR0 + kp,              T + 8192 + dA);
            GLDS16(Alp + aR0 + 16 * EMBED + kp, T + 8192 + dA + 512);
            GLDS16(Bhp + bR0 + kp,              T + 16384 + dB);
            GLDS16(Blp + bR0 + kp,              T + 20480 + dB);
        }
        __builtin_amdgcn_s_setprio(1);
#pragma unroll
        for (int i = 0; i < 4; ++i)
#pragma unroll
            for (int j = 0; j < 4; ++j) {
                acc[i][j] = __builtin_amdgcn_mfma_f32_16x16x32_bf16(fah[i], fbh[j], acc[i][j], 0, 0, 0);
                acc[i][j] = __builtin_amdgcn_mfma_f32_16x16x32_bf16(fah[i], fbl[j], acc[i][j], 0, 0, 0);
                acc[i][j] = __builtin_amdgcn_mfma_f32_16x16x32_bf16(fal[i], fbh[j], acc[i][j], 0, 0, 0);
            }
        __builtin_amdgcn_s_setprio(0);
        rs = (rs == 2) ? 0 : rs + 1;
    }
}

// ---- fused QKV projection GEMM -------------------------------------------
__global__ __launch_bounds__(512, 2)
void qkv_gemm(const short* __restrict__ Aqh, const short* __restrict__ Aql,
              const short* __restrict__ Akh, const short* __restrict__ Akl,
              const short* __restrict__ Avh, const short* __restrict__ Avl,
              const short* __restrict__ WqH, const short* __restrict__ WqL,
              const short* __restrict__ WkH, const short* __restrict__ WkL,
              const short* __restrict__ WvH, const short* __restrict__ WvL,
              float* __restrict__ Qb, float* __restrict__ Kb,
              float* __restrict__ Vb) {
    __shared__ short lds[3][24576];      // 144 KiB ring

    const int lin = blockIdx.x;
    const int op  = lin >> 8;                     // 0=q,1=k,2=v (256 blocks each)
    const int r_  = lin & 255;
    const int bnG = ((r_ >> 6) & 3) * 128;        // bn-major: A-panel stays on XCD
    const int bmG = (r_ & 63) * 256;

    const short* Ah = (op == 0) ? Aqh : (op == 1) ? Akh : Avh;
    const short* Al = (op == 0) ? Aql : (op == 1) ? Akl : Avl;
    const short* Bh = (op == 0) ? WqH : (op == 1) ? WkH : WvH;
    const short* Bl = (op == 0) ? WqL : (op == 1) ? WkL : WvL;
    float* C = (op == 0) ? Qb : (op == 1) ? Kb : Vb;

    f32x4 acc[4][4];
#pragma unroll
    for (int i = 0; i < 4; ++i)
#pragma unroll
        for (int j = 0; j < 4; ++j) acc[i][j] = (f32x4)0.0f;

    gemm_core(Ah, Al, Bh, Bl, bmG, bnG, lds, acc);

    const int lane = threadIdx.x & 63;
    const int wave = threadIdx.x >> 6;
    const int l15  = lane & 15;
    const int kg   = lane >> 4;
    const int wm   = (wave >> 1) * 64;
    const int wn   = (wave & 1) * 64;
#pragma unroll
    for (int i = 0; i < 4; ++i)
#pragma unroll
        for (int j = 0; j < 4; ++j) {
            const int col = bnG + wn + j * 16 + l15;
#pragma unroll
            for (int r = 0; r < 4; ++r) {
                const int row = bmG + wm + i * 16 + kg * 4 + r;
                float vv = acc[i][j][r];
                if (op < 2) vv = (vv > 0.f) ? (vv + 1.f) : __expf(vv);
                else        vv = vv * (1.0f / (float)SEQ);
                C[(size_t)row * EMBED + col] = vv;
            }
        }
}

// ---- merge GEMM: same core, plain store ----------------------------------
__global__ __launch_bounds__(512, 2)
void merge_gemm(const short* __restrict__ Mh, const short* __restrict__ Ml,
                const short* __restrict__ WhP, const short* __restrict__ WlP,
                float* __restrict__ C) {
    __shared__ short lds[3][24576];

    const int lin = blockIdx.x;
    const int bnG = ((lin >> 6) & 3) * 128;
    const int bmG = (lin & 63) * 256;

    f32x4 acc[4][4];
#pragma unroll
    for (int i = 0; i < 4; ++i)
#pragma unroll
        for (int j = 0; j < 4; ++j) acc[i][j] = (f32x4)0.0f;

    gemm_core(Mh, Ml, WhP, WlP, bmG, bnG, lds, acc);

    const int lane = threadIdx.x & 63;
    const int wave = threadIdx.x >> 6;
    const int l15  = lane & 15;
    const int kg   = lane >> 4;
    const int wm   = (wave >> 1) * 64;
    const int wn   = (wave & 1) * 64;
#pragma unroll
    for (int i = 0; i < 4; ++i)
#pragma unroll
        for (int j = 0; j < 4; ++j) {
            const int col = bnG + wn + j * 16 + l15;
#pragma unroll
            for (int r = 0; r < 4; ++r) {
                const int row = bmG + wm + i * 16 + kg * 4 + r;
                C[(size_t)row * EMBED + col] = acc[i][j][r];
            }
        }
}

// ---- KV + Ksum via split-bf16 MFMA (unchanged) ---------------------------
__global__ __launch_bounds__(256)
void kv_ksum_mfma(const float* __restrict__ Kf, const float* __restrict__ Vf,
                  float* __restrict__ KV, float* __restrict__ Ksum) {
    __shared__ char smem[34816];
    short (*Kh)[34] = (short (*)[34])smem;
    short (*Kl)[34] = (short (*)[34])(smem + 8704);
    short (*Vh)[34] = (short (*)[34])(smem + 17408);
    short (*Vl)[34] = (short (*)[34])(smem + 26112);

    const int bh_ = blockIdx.y;
    const int b = bh_ >> 4, h = bh_ & 15;
    const int s0 = blockIdx.x * 256;
    const int t = threadIdx.x;
    const int lane = t & 63, wave = t >> 6;
    const int l15 = lane & 15, kg = lane >> 4;
    const int ws = wave * 32;

    const int sl = t >> 1;
    const int dsel = (t & 1) * 16;
    const float* Kbase = Kf + (size_t)b * SEQ * EMBED + h * HDIM;
    const float* Vbase = Vf + (size_t)b * SEQ * EMBED + h * HDIM;

    f32x4 kvacc[2][2], ksacc[2];
#pragma unroll
    for (int i = 0; i < 2; ++i) {
        ksacc[i] = (f32x4)0.0f;
#pragma unroll
        for (int j = 0; j < 2; ++j) kvacc[i][j] = (f32x4)0.0f;
    }
    short8 ones;
#pragma unroll
    for (int q = 0; q < 8; ++q) ones[q] = (short)0x3F80;   // bf16 1.0

    float4 kx[4], vx[4];
#pragma unroll
    for (int p = 0; p < 4; ++p) {
        kx[p] = *(const float4*)(Kbase + (size_t)(s0 + sl) * EMBED + dsel + 4 * p);
        vx[p] = *(const float4*)(Vbase + (size_t)(s0 + sl) * EMBED + dsel + 4 * p);
    }

#pragma unroll 1
    for (int it = 0; it < 2; ++it) {
        __syncthreads();
        {
            float kv_[8] = {kx[0].x, kx[0].y, kx[0].z, kx[0].w, kx[1].x, kx[1].y, kx[1].z, kx[1].w};
            float kv2[8] = {kx[2].x, kx[2].y, kx[2].z, kx[2].w, kx[3].x, kx[3].y, kx[3].z, kx[3].w};
            float vv_[8] = {vx[0].x, vx[0].y, vx[0].z, vx[0].w, vx[1].x, vx[1].y, vx[1].z, vx[1].w};
            float vv2[8] = {vx[2].x, vx[2].y, vx[2].z, vx[2].w, vx[3].x, vx[3].y, vx[3].z, vx[3].w};
            short8 h0, l0, h1, l1;
#pragma unroll
            for (int q = 0; q < 8; ++q) { short hb = f2bf(kv_[q]); h0[q] = hb; l0[q] = f2bf(kv_[q] - bf2f(hb)); }
#pragma unroll
            for (int q = 0; q < 8; ++q) { short hb = f2bf(kv2[q]); h1[q] = hb; l1[q] = f2bf(kv2[q] - bf2f(hb)); }
            *(short8*)&Kh[sl][dsel] = h0; *(short8*)&Kh[sl][dsel + 8] = h1;
            *(short8*)&Kl[sl][dsel] = l0; *(short8*)&Kl[sl][dsel + 8] = l1;
#pragma unroll
            for (int q = 0; q < 8; ++q) { short hb = f2bf(vv_[q]); h0[q] = hb; l0[q] = f2bf(vv_[q] - bf2f(hb)); }
#pragma unroll
            for (int q = 0; q < 8; ++q) { short hb = f2bf(vv2[q]); h1[q] = hb; l1[q] = f2bf(vv2[q] - bf2f(hb)); }
            *(short8*)&Vh[sl][dsel] = h0; *(short8*)&Vh[sl][dsel + 8] = h1;
            *(short8*)&Vl[sl][dsel] = l0; *(short8*)&Vl[sl][dsel + 8] = l1;
        }
        __syncthreads();
        if (it == 0) {
#pragma unroll
            for (int p = 0; p < 4; ++p) {
                kx[p] = *(const float4*)(Kbase + (size_t)(s0 + 128 + sl) * EMBED + dsel + 4 * p);
                vx[p] = *(const float4*)(Vbase + (size_t)(s0 + 128 + sl) * EMBED + dsel + 4 * p);
            }
        }
        short8 kah[2], kal[2], vbh[2], vbl[2];
#pragma unroll
        for (int i = 0; i < 2; ++i) {
#pragma unroll
            for (int q = 0; q < 8; ++q) {
                const int srow = ws + kg * 8 + q;
                const int col  = i * 16 + l15;
                kah[i][q] = Kh[srow][col];
                kal[i][q] = Kl[srow][col];
                vbh[i][q] = Vh[srow][col];
                vbl[i][q] = Vl[srow][col];
            }
        }
#pragma unroll
        for (int i = 0; i < 2; ++i) {
#pragma unroll
            for (int j = 0; j < 2; ++j) {
                kvacc[i][j] = __builtin_amdgcn_mfma_f32_16x16x32_bf16(kah[i], vbh[j], kvacc[i][j], 0, 0, 0);
                kvacc[i][j] = __builtin_amdgcn_mfma_f32_16x16x32_bf16(kah[i], vbl[j], kvacc[i][j], 0, 0, 0);
                kvacc[i][j] = __builtin_amdgcn_mfma_f32_16x16x32_bf16(kal[i], vbh[j], kvacc[i][j], 0, 0, 0);
            }
            ksacc[i] = __builtin_amdgcn_mfma_f32_16x16x32_bf16(kah[i], ones, ksacc[i], 0, 0, 0);
            ksacc[i] = __builtin_amdgcn_mfma_f32_16x16x32_bf16(kal[i], ones, ksacc[i], 0, 0, 0);
        }
    }

    __syncthreads();
    float* red = (float*)smem;
    float* myred = red + wave * 1056;
#pragma unroll
    for (int i = 0; i < 2; ++i)
#pragma unroll
        for (int j = 0; j < 2; ++j)
#pragma unroll
            for (int r = 0; r < 4; ++r)
                myred[(i * 16 + kg * 4 + r) * 32 + j * 16 + l15] = kvacc[i][j][r];
    if (l15 == 0) {
#pragma unroll
        for (int i = 0; i < 2; ++i)
#pragma unroll
            for (int r = 0; r < 4; ++r)
                myred[1024 + i * 16 + kg * 4 + r] = ksacc[i][r];
    }
    __syncthreads();
    float* kvout = KV + (size_t)bh_ * 1024;
    for (int idx = t; idx < 1024; idx += 256) {
        float s4 = red[idx] + red[1056 + idx] + red[2112 + idx] + red[3168 + idx];
        atomicAdd(&kvout[idx], s4);
    }
    if (t < 32) {
        float s4 = red[1024 + t] + red[1056 + 1024 + t] + red[2112 + 1024 + t] + red[3168 + 1024 + t];
        atomicAdd(&Ksum[bh_ * 32 + t], s4);
    }
}

// ---- message: M[l,h,:] = (SEQ/(Q.Ksum+eps)) * Q @ KV[b,h], emit split bf16
__global__ __launch_bounds__(512)
void message_kernel(const float* __restrict__ Q, const float* __restrict__ KV,
                    const float* __restrict__ Ksum,
                    short* __restrict__ Mh, short* __restrict__ Ml) {
    const int blk  = blockIdx.x;
    const int row0 = blk * 4;
    const int b    = row0 >> 12;
    const int t    = threadIdx.x;
    const int h    = t >> 5, e = t & 31;

    __shared__ float q[4][EMBED];
    __shared__ float ks[EMBED];
    ks[t] = Ksum[b * EMBED + t];
#pragma unroll
    for (int r = 0; r < 4; ++r) q[r][t] = Q[(size_t)(row0 + r) * EMBED + t];

    const float* kvh = KV + (size_t)(b * NHEAD + h) * HDIM * HDIM + e;
    float kc[HDIM];
#pragma unroll
    for (int d = 0; d < HDIM; ++d) kc[d] = kvh[d * HDIM];
    __syncthreads();

#pragma unroll
    for (int r = 0; r < 4; ++r) {
        float zden = FEPS, m = 0.f;
#pragma unroll
        for (int d = 0; d < HDIM; ++d) {
            float qd = q[r][h * HDIM + d];
            zden = fmaf(qd, ks[h * HDIM + d], zden);
            m    = fmaf(qd, kc[d], m);
        }
        float vv = m * ((float)SEQ / zden);
        short hb = f2bf(vv);
        Mh[(size_t)(row0 + r) * EMBED + t] = hb;
        Ml[(size_t)(row0 + r) * EMBED + t] = f2bf(vv - bf2f(hb));
    }
}

// ---- launch ----
extern "C" void kernel_launch(void* const* d_in, const int* in_sizes, int n_in,
                              void* d_out, int out_size, void* d_ws, size_t ws_size,
                              hipStream_t stream) {
    const float* query = (const float*)d_in[0];
    const float* key   = (const float*)d_in[1];
    const float* value = (const float*)d_in[2];
    const float* Wq    = (const float*)d_in[3];
    const float* Wk    = (const float*)d_in[4];
    const float* Wv    = (const float*)d_in[5];
    const float* Wm    = (const float*)d_in[6];
    float* out = (float*)d_out;

    float* ws  = (float*)d_ws;
    float* Qb  = ws;                              // NE fp32
    float* Kb  = Qb + (size_t)NE;                 // NE fp32 (reused as M planes)
    float* Vb  = Kb + (size_t)NE;                 // NE fp32
    float* KVb = Vb + (size_t)NE;                 // 64*1024
    float* KSb = KVb + 64 * 1024;                 // 64*32
    short* wsp = (short*)(KSb + 64 * HDIM);
    short* WqH = wsp;            short* WqL = wsp + WN;
    short* WkH = wsp + 2 * WN;   short* WkL = wsp + 3 * WN;
    short* WvH = wsp + 4 * WN;   short* WvL = wsp + 5 * WN;
    short* WmH = wsp + 6 * WN;   short* WmL = wsp + 7 * WN;
    short* Xp  = wsp + 8 * WN;                    // 6 input planes, NE shorts each
    short* Qih = Xp;             short* Qil = Xp + (size_t)NE;
    short* Kih = Xp + 2 * (size_t)NE;  short* Kil = Xp + 3 * (size_t)NE;
    short* Vih = Xp + 4 * (size_t)NE;  short* Vil = Xp + 5 * (size_t)NE;
    // message planes alias Kb (dead after kv_ksum): 2*NE shorts == NE floats
    short* Mh = (short*)Kb;
    short* Ml = Mh + (size_t)NE;

    hipMemsetAsync(KVb, 0, (64 * 1024 + 64 * HDIM) * sizeof(float), stream);

    convert_all<<<12800, 256, 0, stream>>>(query, key, value, Wq, Wk, Wv, Wm,
                                           Qih, Qil, Kih, Kil, Vih, Vil,
                                           WqH, WqL, WkH, WkL,
                                           WvH, WvL, WmH, WmL);

    qkv_gemm<<<768, 512, 0, stream>>>(Qih, Qil, Kih, Kil, Vih, Vil,
                                      WqH, WqL, WkH, WkL, WvH, WvL,
                                      Qb, Kb, Vb);

    kv_ksum_mfma<<<dim3(16, 64), 256, 0, stream>>>(Kb, Vb, KVb, KSb);
    message_kernel<<<NROWS / 4, 512, 0, stream>>>(Qb, KVb, KSb, Mh, Ml);

    merge_gemm<<<256, 512, 0, stream>>>(Mh, Ml, WmH, WmL, out);
}

// Round 3
// 295.004 us; speedup vs baseline: 1.1078x; 1.0274x over previous
//
#include <hip/hip_runtime.h>

// Problem constants (B=4, L=4096, E=512, H=16, D=32)
#define EMBED  512
#define NHEAD  16
#define HDIM   32
#define NBATCH 4
#define SEQ    4096
#define NROWS  (NBATCH * SEQ)   // 16384
#define NE     (NROWS * EMBED)  // 8388608 elements per activation tensor
#define WN     (EMBED * EMBED)  // 262144 elements per weight
#define FEPS   1e-6f

typedef __attribute__((ext_vector_type(8))) short short8;
typedef __attribute__((ext_vector_type(4))) float f32x4;

// ---- bf16 split helpers (RNE) ----
__device__ __forceinline__ short f2bf(float x) {
    unsigned u = __float_as_uint(x);
    u += 0x7FFFu + ((u >> 16) & 1u);
    return (short)(u >> 16);
}
__device__ __forceinline__ float bf2f(short h) {
    return __uint_as_float(((unsigned)(unsigned short)h) << 16);
}

// async global->LDS, 16B per lane, wave-uniform LDS base + lane*16
#define GLDS16(gp, lp)                                                   \
    __builtin_amdgcn_global_load_lds(                                    \
        (__attribute__((address_space(1))) void*)(void*)(gp),            \
        (__attribute__((address_space(3))) void*)(void*)(lp), 16, 0, 0)

#define SBAR()  do { __builtin_amdgcn_s_barrier();                        \
                     __builtin_amdgcn_sched_barrier(0); } while (0)

// ---- convert everything fp32 -> split bf16 + zero KV/Ksum, one pass ------
__global__ __launch_bounds__(256)
void convert_all(const float* __restrict__ q, const float* __restrict__ k,
                 const float* __restrict__ v,
                 const float* __restrict__ wq, const float* __restrict__ wk,
                 const float* __restrict__ wv, const float* __restrict__ wm,
                 short* __restrict__ qh, short* __restrict__ ql,
                 short* __restrict__ kh, short* __restrict__ kl,
                 short* __restrict__ vh, short* __restrict__ vl,
                 short* __restrict__ wqh, short* __restrict__ wql,
                 short* __restrict__ wkh, short* __restrict__ wkl,
                 short* __restrict__ wvh, short* __restrict__ wvl,
                 short* __restrict__ wmh, short* __restrict__ wml,
                 float* __restrict__ zeroDst) {
    const int b = blockIdx.x;
    if (b >= 12800) {                    // fused memset: KVb + KSb = 67584 f32
        const int nvec = (64 * 1024 + 64 * HDIM) / 4;   // 16896 float4
        float4 z = {0.f, 0.f, 0.f, 0.f};
        for (int i = (b - 12800) * 256 + threadIdx.x; i < nvec; i += 16 * 256)
            ((float4*)zeroDst)[i] = z;
        return;
    }
    const float* src; short* dh; short* dl; int boff;
    if (b < 12288) {
        const int s = b >> 12;
        src = (s == 0) ? q  : (s == 1) ? k  : v;
        dh  = (s == 0) ? qh : (s == 1) ? kh : vh;
        dl  = (s == 0) ? ql : (s == 1) ? kl : vl;
        boff = b & 4095;
    } else {
        const int s = (b - 12288) >> 7;
        src = (s == 0) ? wq  : (s == 1) ? wk  : (s == 2) ? wv  : wm;
        dh  = (s == 0) ? wqh : (s == 1) ? wkh : (s == 2) ? wvh : wmh;
        dl  = (s == 0) ? wql : (s == 1) ? wkl : (s == 2) ? wvl : wml;
        boff = (b - 12288) & 127;
    }
    const size_t i = ((size_t)boff * 256 + threadIdx.x) * 8;
    float4 x0 = *(const float4*)(src + i);
    float4 x1 = *(const float4*)(src + i + 4);
    float vv[8] = {x0.x, x0.y, x0.z, x0.w, x1.x, x1.y, x1.z, x1.w};
    short8 h, l;
#pragma unroll
    for (int t = 0; t < 8; ++t) {
        short hb = f2bf(vv[t]);
        h[t] = hb;
        l[t] = f2bf(vv[t] - bf2f(hb));
    }
    *(short8*)(dh + i) = h;
    *(short8*)(dl + i) = l;
}

// ---- K-sliced ring-3 GEMM core, fine-interleaved sub-phases --------------
// BM=256 x BN=128, 8 waves (4M x 2N), per-wave 64x64 (4x4 frags). K = 16
// slices of 32. Ring: 3 x 48KB slots. Slice-top gate: vmcnt(6) + barrier
// (slice s resident; s+1 in flight). Then 3 sub-phases per slice:
//   sp0: ds_read 8 frags (a01,b01 hi/lo) + 2 glds -> bar -> prio1 12 MFMA
//   sp1: ds_read 4 frags (b23 hi/lo)      + 2 glds -> bar -> prio1 12 MFMA
//   sp2: ds_read 4 frags (a23 hi/lo)      + 2 glds -> bar -> prio1 24 MFMA
// Fine interleave creates wave role-split (loads vs MFMA) so setprio can
// arbitrate; barriers are convergence-only (no drain). sched_barrier(0)
// after each s_barrier pins glds below the barrier (slot-reuse safety:
// slice s+2 writes slot (s-1)%3 whose readers all passed the slice-s gate).
__device__ __forceinline__ void gemm_core(
    const short* __restrict__ Ahp, const short* __restrict__ Alp,
    const short* __restrict__ Bhp, const short* __restrict__ Blp,
    int bmG, int bnG, short (*lds)[24576], f32x4 acc[4][4])
{
    const int tid  = threadIdx.x;
    const int lane = tid & 63;
    const int wave = tid >> 6;          // 0..7
    const int l15  = lane & 15;
    const int kg   = lane >> 4;

    // staging source bases (shorts), pre-swizzled chunk
    const int sc8 = (((lane & 3) ^ ((lane >> 3) & 3)) << 3);
    const size_t aR0 = (size_t)(bmG + wave * 32 + (lane >> 2)) * EMBED + sc8;
    const size_t bR0 = (size_t)(bnG + wave * 16 + (lane >> 2)) * EMBED + sc8;

    // LDS staging dest offsets within a slot (shorts)
    const int dA = wave * 1024;
    const int dB = wave * 512;

    // fragment read offsets (de-swizzle)
    const int rk8   = ((kg ^ ((l15 >> 1) & 3)) << 3);
    const int aBase = ((wave >> 1) * 64 + l15) * 32 + rk8;          // Ah; Al = +8192
    const int bBase = 16384 + ((wave & 1) * 64 + l15) * 32 + rk8;   // Bh; Bl = +4096

    // prologue: stage slices 0,1 into slots 0,1
#pragma unroll
    for (int v = 0; v < 2; ++v) {
        short* T = lds[v];
        const int kp = v * 32;
        GLDS16(Ahp + aR0 + kp,              T + dA);
        GLDS16(Ahp + aR0 + 16 * EMBED + kp, T + dA + 512);
        GLDS16(Alp + aR0 + kp,              T + 8192 + dA);
        GLDS16(Alp + aR0 + 16 * EMBED + kp, T + 8192 + dA + 512);
        GLDS16(Bhp + bR0 + kp,              T + 16384 + dB);
        GLDS16(Blp + bR0 + kp,              T + 20480 + dB);
    }

#define MFMA3(i, j)                                                                            \
    acc[i][j] = __builtin_amdgcn_mfma_f32_16x16x32_bf16(fah[i], fbh[j], acc[i][j], 0, 0, 0);   \
    acc[i][j] = __builtin_amdgcn_mfma_f32_16x16x32_bf16(fah[i], fbl[j], acc[i][j], 0, 0, 0);   \
    acc[i][j] = __builtin_amdgcn_mfma_f32_16x16x32_bf16(fal[i], fbh[j], acc[i][j], 0, 0, 0);

    int rs = 0;                          // read slot = s % 3
#pragma unroll 1
    for (int s = 0; s < 16; ++s) {
        // ---- slice-top gate: slice s resident, s+1 in flight ----
        if (s < 15) asm volatile("s_waitcnt vmcnt(6)" ::: "memory");
        else        asm volatile("s_waitcnt vmcnt(0)" ::: "memory");
        SBAR();

        short* S = lds[rs];
        const int ws2 = (rs + 2 >= 3) ? (rs - 1) : (rs + 2);
        short* T = lds[ws2];
        const int kp = (s + 2) * 32;
        const bool st = (s < 14);

        short8 fah[4], fal[4], fbh[4], fbl[4];

        // ---- sub-phase 0: a01/b01 hi+lo (8 reads) + 2 A-hi glds ----
#pragma unroll
        for (int f = 0; f < 2; ++f) {
            fah[f] = *(const short8*)(S + aBase + f * 512);
            fal[f] = *(const short8*)(S + 8192 + aBase + f * 512);
            fbh[f] = *(const short8*)(S + bBase + f * 512);
            fbl[f] = *(const short8*)(S + 4096 + bBase + f * 512);
        }
        if (st) {
            GLDS16(Ahp + aR0 + kp,              T + dA);
            GLDS16(Ahp + aR0 + 16 * EMBED + kp, T + dA + 512);
        }
        SBAR();
        __builtin_amdgcn_s_setprio(1);
        MFMA3(0, 0) MFMA3(0, 1) MFMA3(1, 0) MFMA3(1, 1)
        __builtin_amdgcn_s_setprio(0);

        // ---- sub-phase 1: b23 hi+lo (4 reads) + 2 A-lo glds ----
#pragma unroll
        for (int f = 2; f < 4; ++f) {
            fbh[f] = *(const short8*)(S + bBase + f * 512);
            fbl[f] = *(const short8*)(S + 4096 + bBase + f * 512);
        }
        if (st) {
            GLDS16(Alp + aR0 + kp,              T + 8192 + dA);
            GLDS16(Alp + aR0 + 16 * EMBED + kp, T + 8192 + dA + 512);
        }
        SBAR();
        __builtin_amdgcn_s_setprio(1);
        MFMA3(0, 2) MFMA3(0, 3) MFMA3(1, 2) MFMA3(1, 3)
        __builtin_amdgcn_s_setprio(0);

        // ---- sub-phase 2: a23 hi+lo (4 reads) + 2 B glds, 24 MFMA ----
#pragma unroll
        for (int f = 2; f < 4; ++f) {
            fah[f] = *(const short8*)(S + aBase + f * 512);
            fal[f] = *(const short8*)(S + 8192 + aBase + f * 512);
        }
        if (st) {
            GLDS16(Bhp + bR0 + kp, T + 16384 + dB);
            GLDS16(Blp + bR0 + kp, T + 20480 + dB);
        }
        SBAR();
        __builtin_amdgcn_s_setprio(1);
        MFMA3(2, 0) MFMA3(2, 1) MFMA3(3, 0) MFMA3(3, 1)
        MFMA3(2, 2) MFMA3(2, 3) MFMA3(3, 2) MFMA3(3, 3)
        __builtin_amdgcn_s_setprio(0);

        rs = (rs == 2) ? 0 : rs + 1;
    }
#undef MFMA3
}

// ---- fused QKV projection GEMM -------------------------------------------
__global__ __launch_bounds__(512, 2)
void qkv_gemm(const short* __restrict__ Aqh, const short* __restrict__ Aql,
              const short* __restrict__ Akh, const short* __restrict__ Akl,
              const short* __restrict__ Avh, const short* __restrict__ Avl,
              const short* __restrict__ WqH, const short* __restrict__ WqL,
              const short* __restrict__ WkH, const short* __restrict__ WkL,
              const short* __restrict__ WvH, const short* __restrict__ WvL,
              float* __restrict__ Qb, float* __restrict__ Kb,
              float* __restrict__ Vb) {
    __shared__ short lds[3][24576];      // 144 KiB ring

    const int lin = blockIdx.x;
    const int op  = lin >> 8;                     // 0=q,1=k,2=v (256 blocks each)
    const int r_  = lin & 255;
    const int bnG = ((r_ >> 6) & 3) * 128;        // bn-major: A-panel stays on XCD
    const int bmG = (r_ & 63) * 256;

    const short* Ah = (op == 0) ? Aqh : (op == 1) ? Akh : Avh;
    const short* Al = (op == 0) ? Aql : (op == 1) ? Akl : Avl;
    const short* Bh = (op == 0) ? WqH : (op == 1) ? WkH : WvH;
    const short* Bl = (op == 0) ? WqL : (op == 1) ? WkL : WvL;
    float* C = (op == 0) ? Qb : (op == 1) ? Kb : Vb;

    f32x4 acc[4][4];
#pragma unroll
    for (int i = 0; i < 4; ++i)
#pragma unroll
        for (int j = 0; j < 4; ++j) acc[i][j] = (f32x4)0.0f;

    gemm_core(Ah, Al, Bh, Bl, bmG, bnG, lds, acc);

    const int lane = threadIdx.x & 63;
    const int wave = threadIdx.x >> 6;
    const int l15  = lane & 15;
    const int kg   = lane >> 4;
    const int wm   = (wave >> 1) * 64;
    const int wn   = (wave & 1) * 64;
#pragma unroll
    for (int i = 0; i < 4; ++i)
#pragma unroll
        for (int j = 0; j < 4; ++j) {
            const int col = bnG + wn + j * 16 + l15;
#pragma unroll
            for (int r = 0; r < 4; ++r) {
                const int row = bmG + wm + i * 16 + kg * 4 + r;
                float vv = acc[i][j][r];
                if (op < 2) vv = (vv > 0.f) ? (vv + 1.f) : __expf(vv);
                else        vv = vv * (1.0f / (float)SEQ);
                C[(size_t)row * EMBED + col] = vv;
            }
        }
}

// ---- merge GEMM: same core, plain store ----------------------------------
__global__ __launch_bounds__(512, 2)
void merge_gemm(const short* __restrict__ Mh, const short* __restrict__ Ml,
                const short* __restrict__ WhP, const short* __restrict__ WlP,
                float* __restrict__ C) {
    __shared__ short lds[3][24576];

    const int lin = blockIdx.x;
    const int bnG = ((lin >> 6) & 3) * 128;
    const int bmG = (lin & 63) * 256;

    f32x4 acc[4][4];
#pragma unroll
    for (int i = 0; i < 4; ++i)
#pragma unroll
        for (int j = 0; j < 4; ++j) acc[i][j] = (f32x4)0.0f;

    gemm_core(Mh, Ml, WhP, WlP, bmG, bnG, lds, acc);

    const int lane = threadIdx.x & 63;
    const int wave = threadIdx.x >> 6;
    const int l15  = lane & 15;
    const int kg   = lane >> 4;
    const int wm   = (wave >> 1) * 64;
    const int wn   = (wave & 1) * 64;
#pragma unroll
    for (int i = 0; i < 4; ++i)
#pragma unroll
        for (int j = 0; j < 4; ++j) {
            const int col = bnG + wn + j * 16 + l15;
#pragma unroll
            for (int r = 0; r < 4; ++r) {
                const int row = bmG + wm + i * 16 + kg * 4 + r;
                C[(size_t)row * EMBED + col] = acc[i][j][r];
            }
        }
}

// ---- KV + Ksum via split-bf16 MFMA (unchanged) ---------------------------
__global__ __launch_bounds__(256)
void kv_ksum_mfma(const float* __restrict__ Kf, const float* __restrict__ Vf,
                  float* __restrict__ KV, float* __restrict__ Ksum) {
    __shared__ char smem[34816];
    short (*Kh)[34] = (short (*)[34])smem;
    short (*Kl)[34] = (short (*)[34])(smem + 8704);
    short (*Vh)[34] = (short (*)[34])(smem + 17408);
    short (*Vl)[34] = (short (*)[34])(smem + 26112);

    const int bh_ = blockIdx.y;
    const int b = bh_ >> 4, h = bh_ & 15;
    const int s0 = blockIdx.x * 256;
    const int t = threadIdx.x;
    const int lane = t & 63, wave = t >> 6;
    const int l15 = lane & 15, kg = lane >> 4;
    const int ws = wave * 32;

    const int sl = t >> 1;
    const int dsel = (t & 1) * 16;
    const float* Kbase = Kf + (size_t)b * SEQ * EMBED + h * HDIM;
    const float* Vbase = Vf + (size_t)b * SEQ * EMBED + h * HDIM;

    f32x4 kvacc[2][2], ksacc[2];
#pragma unroll
    for (int i = 0; i < 2; ++i) {
        ksacc[i] = (f32x4)0.0f;
#pragma unroll
        for (int j = 0; j < 2; ++j) kvacc[i][j] = (f32x4)0.0f;
    }
    short8 ones;
#pragma unroll
    for (int q = 0; q < 8; ++q) ones[q] = (short)0x3F80;   // bf16 1.0

    float4 kx[4], vx[4];
#pragma unroll
    for (int p = 0; p < 4; ++p) {
        kx[p] = *(const float4*)(Kbase + (size_t)(s0 + sl) * EMBED + dsel + 4 * p);
        vx[p] = *(const float4*)(Vbase + (size_t)(s0 + sl) * EMBED + dsel + 4 * p);
    }

#pragma unroll 1
    for (int it = 0; it < 2; ++it) {
        __syncthreads();
        {
            float kv_[8] = {kx[0].x, kx[0].y, kx[0].z, kx[0].w, kx[1].x, kx[1].y, kx[1].z, kx[1].w};
            float kv2[8] = {kx[2].x, kx[2].y, kx[2].z, kx[2].w, kx[3].x, kx[3].y, kx[3].z, kx[3].w};
            float vv_[8] = {vx[0].x, vx[0].y, vx[0].z, vx[0].w, vx[1].x, vx[1].y, vx[1].z, vx[1].w};
            float vv2[8] = {vx[2].x, vx[2].y, vx[2].z, vx[2].w, vx[3].x, vx[3].y, vx[3].z, vx[3].w};
            short8 h0, l0, h1, l1;
#pragma unroll
            for (int q = 0; q < 8; ++q) { short hb = f2bf(kv_[q]); h0[q] = hb; l0[q] = f2bf(kv_[q] - bf2f(hb)); }
#pragma unroll
            for (int q = 0; q < 8; ++q) { short hb = f2bf(kv2[q]); h1[q] = hb; l1[q] = f2bf(kv2[q] - bf2f(hb)); }
            *(short8*)&Kh[sl][dsel] = h0; *(short8*)&Kh[sl][dsel + 8] = h1;
            *(short8*)&Kl[sl][dsel] = l0; *(short8*)&Kl[sl][dsel + 8] = l1;
#pragma unroll
            for (int q = 0; q < 8; ++q) { short hb = f2bf(vv_[q]); h0[q] = hb; l0[q] = f2bf(vv_[q] - bf2f(hb)); }
#pragma unroll
            for (int q = 0; q < 8; ++q) { short hb = f2bf(vv2[q]); h1[q] = hb; l1[q] = f2bf(vv2[q] - bf2f(hb)); }
            *(short8*)&Vh[sl][dsel] = h0; *(short8*)&Vh[sl][dsel + 8] = h1;
            *(short8*)&Vl[sl][dsel] = l0; *(short8*)&Vl[sl][dsel + 8] = l1;
        }
        __syncthreads();
        if (it == 0) {
#pragma unroll
            for (int p = 0; p < 4; ++p) {
                kx[p] = *(const float4*)(Kbase + (size_t)(s0 + 128 + sl) * EMBED + dsel + 4 * p);
                vx[p] = *(const float4*)(Vbase + (size_t)(s0 + 128 + sl) * EMBED + dsel + 4 * p);
            }
        }
        short8 kah[2], kal[2], vbh[2], vbl[2];
#pragma unroll
        for (int i = 0; i < 2; ++i) {
#pragma unroll
            for (int q = 0; q < 8; ++q) {
                const int srow = ws + kg * 8 + q;
                const int col  = i * 16 + l15;
                kah[i][q] = Kh[srow][col];
                kal[i][q] = Kl[srow][col];
                vbh[i][q] = Vh[srow][col];
                vbl[i][q] = Vl[srow][col];
            }
        }
#pragma unroll
        for (int i = 0; i < 2; ++i) {
#pragma unroll
            for (int j = 0; j < 2; ++j) {
                kvacc[i][j] = __builtin_amdgcn_mfma_f32_16x16x32_bf16(kah[i], vbh[j], kvacc[i][j], 0, 0, 0);
                kvacc[i][j] = __builtin_amdgcn_mfma_f32_16x16x32_bf16(kah[i], vbl[j], kvacc[i][j], 0, 0, 0);
                kvacc[i][j] = __builtin_amdgcn_mfma_f32_16x16x32_bf16(kal[i], vbh[j], kvacc[i][j], 0, 0, 0);
            }
            ksacc[i] = __builtin_amdgcn_mfma_f32_16x16x32_bf16(kah[i], ones, ksacc[i], 0, 0, 0);
            ksacc[i] = __builtin_amdgcn_mfma_f32_16x16x32_bf16(kal[i], ones, ksacc[i], 0, 0, 0);
        }
    }

    __syncthreads();
    float* red = (float*)smem;
    float* myred = red + wave * 1056;
#pragma unroll
    for (int i = 0; i < 2; ++i)
#pragma unroll
        for (int j = 0; j < 2; ++j)
#pragma unroll
            for (int r = 0; r < 4; ++r)
                myred[(i * 16 + kg * 4 + r) * 32 + j * 16 + l15] = kvacc[i][j][r];
    if (l15 == 0) {
#pragma unroll
        for (int i = 0; i < 2; ++i)
#pragma unroll
            for (int r = 0; r < 4; ++r)
                myred[1024 + i * 16 + kg * 4 + r] = ksacc[i][r];
    }
    __syncthreads();
    float* kvout = KV + (size_t)bh_ * 1024;
    for (int idx = t; idx < 1024; idx += 256) {
        float s4 = red[idx] + red[1056 + idx] + red[2112 + idx] + red[3168 + idx];
        atomicAdd(&kvout[idx], s4);
    }
    if (t < 32) {
        float s4 = red[1024 + t] + red[1056 + 1024 + t] + red[2112 + 1024 + t] + red[3168 + 1024 + t];
        atomicAdd(&Ksum[bh_ * 32 + t], s4);
    }
}

// ---- message: M[l,h,:] = (SEQ/(Q.Ksum+eps)) * Q @ KV[b,h], emit split bf16
__global__ __launch_bounds__(512)
void message_kernel(const float* __restrict__ Q, const float* __restrict__ KV,
                    const float* __restrict__ Ksum,
                    short* __restrict__ Mh, short* __restrict__ Ml) {
    const int blk  = blockIdx.x;
    const int row0 = blk * 4;
    const int b    = row0 >> 12;
    const int t    = threadIdx.x;
    const int h    = t >> 5, e = t & 31;

    __shared__ float q[4][EMBED];
    __shared__ float ks[EMBED];
    ks[t] = Ksum[b * EMBED + t];
#pragma unroll
    for (int r = 0; r < 4; ++r) q[r][t] = Q[(size_t)(row0 + r) * EMBED + t];

    const float* kvh = KV + (size_t)(b * NHEAD + h) * HDIM * HDIM + e;
    float kc[HDIM];
#pragma unroll
    for (int d = 0; d < HDIM; ++d) kc[d] = kvh[d * HDIM];
    __syncthreads();

#pragma unroll
    for (int r = 0; r < 4; ++r) {
        float zden = FEPS, m = 0.f;
#pragma unroll
        for (int d = 0; d < HDIM; ++d) {
            float qd = q[r][h * HDIM + d];
            zden = fmaf(qd, ks[h * HDIM + d], zden);
            m    = fmaf(qd, kc[d], m);
        }
        float vv = m * ((float)SEQ / zden);
        short hb = f2bf(vv);
        Mh[(size_t)(row0 + r) * EMBED + t] = hb;
        Ml[(size_t)(row0 + r) * EMBED + t] = f2bf(vv - bf2f(hb));
    }
}

// ---- launch ----
extern "C" void kernel_launch(void* const* d_in, const int* in_sizes, int n_in,
                              void* d_out, int out_size, void* d_ws, size_t ws_size,
                              hipStream_t stream) {
    const float* query = (const float*)d_in[0];
    const float* key   = (const float*)d_in[1];
    const float* value = (const float*)d_in[2];
    const float* Wq    = (const float*)d_in[3];
    const float* Wk    = (const float*)d_in[4];
    const float* Wv    = (const float*)d_in[5];
    const float* Wm    = (const float*)d_in[6];
    float* out = (float*)d_out;

    float* ws  = (float*)d_ws;
    float* Qb  = ws;                              // NE fp32
    float* Kb  = Qb + (size_t)NE;                 // NE fp32 (reused as M planes)
    float* Vb  = Kb + (size_t)NE;                 // NE fp32
    float* KVb = Vb + (size_t)NE;                 // 64*1024
    float* KSb = KVb + 64 * 1024;                 // 64*32
    short* wsp = (short*)(KSb + 64 * HDIM);
    short* WqH = wsp;            short* WqL = wsp + WN;
    short* WkH = wsp + 2 * WN;   short* WkL = wsp + 3 * WN;
    short* WvH = wsp + 4 * WN;   short* WvL = wsp + 5 * WN;
    short* WmH = wsp + 6 * WN;   short* WmL = wsp + 7 * WN;
    short* Xp  = wsp + 8 * WN;                    // 6 input planes, NE shorts each
    short* Qih = Xp;             short* Qil = Xp + (size_t)NE;
    short* Kih = Xp + 2 * (size_t)NE;  short* Kil = Xp + 3 * (size_t)NE;
    short* Vih = Xp + 4 * (size_t)NE;  short* Vil = Xp + 5 * (size_t)NE;
    // message planes alias Kb (dead after kv_ksum): 2*NE shorts == NE floats
    short* Mh = (short*)Kb;
    short* Ml = Mh + (size_t)NE;

    convert_all<<<12816, 256, 0, stream>>>(query, key, value, Wq, Wk, Wv, Wm,
                                           Qih, Qil, Kih, Kil, Vih, Vil,
                                           WqH, WqL, WkH, WkL,
                                           WvH, WvL, WmH, WmL, KVb);

    qkv_gemm<<<768, 512, 0, stream>>>(Qih, Qil, Kih, Kil, Vih, Vil,
                                      WqH, WqL, WkH, WkL, WvH, WvL,
                                      Qb, Kb, Vb);

    kv_ksum_mfma<<<dim3(16, 64), 256, 0, stream>>>(Kb, Vb, KVb, KSb);
    message_kernel<<<NROWS / 4, 512, 0, stream>>>(Qb, KVb, KSb, Mh, Ml);

    merge_gemm<<<256, 512, 0, stream>>>(Mh, Ml, WmH, WmL, out);
}